// Round 12
// baseline (1596.181 us; speedup 1.0000x reference)
//
#include <hip/hip_runtime.h>
#include <hip/hip_cooperative_groups.h>
#include <hip/hip_bf16.h>
#include <math.h>

namespace cg = cooperative_groups;

#define DV 256
#define NSEQ 1024
#define HHEADS 8
#define VV 32000
#define QKSCALE 0.17677669529663687f  // 1/sqrt(32)

typedef __attribute__((ext_vector_type(8))) short short8v;
typedef __attribute__((ext_vector_type(4))) float f32x4;

__device__ __forceinline__ unsigned short f2bf(float f){
  __hip_bfloat16 b = __float2bfloat16(f);
  return *reinterpret_cast<unsigned short*>(&b);
}
__device__ __forceinline__ float bfbits2f(unsigned short u){
  unsigned int x = ((unsigned int)u) << 16;
  return __uint_as_float(x);
}
__device__ __forceinline__ int xcd_swz(int lin, int nwg){
  return (lin & 7) * (nwg >> 3) + (lin >> 3);
}

#define OFF_WQKVP 0
#define OFF_WOT   425984
#define OFF_F1T   557056
#define OFF_F2T   1081344

// ==================== pre-kernels (always dispatched) ====================

__global__ __launch_bounds__(256) void transpose_cvt_all(
    const float* __restrict__ Wq, const float* __restrict__ Wk,
    const float* __restrict__ Wv, const float* __restrict__ Wo,
    const float* __restrict__ ppw, const float* __restrict__ f1w,
    const float* __restrict__ f2w, __hip_bfloat16* __restrict__ dst){
  __shared__ float sh[32][33];
  int bid = blockIdx.x;
  int t = threadIdx.x;
  if(bid >= 512 && bid < 528){
    int idx = bid - 512;
    int l = idx >> 3, k0 = (idx & 7) * 32;
    int rowo = t >> 2;
    int kbase = k0 + (t & 3) * 8;
    unsigned short vals[8];
    if(rowo < 8){
      int hh = rowo;
      #pragma unroll
      for(int i=0;i<8;i++) vals[i] = f2bf(ppw[(long)l*2048 + (kbase+i)*HHEADS + hh]);
    } else {
      #pragma unroll
      for(int i=0;i<8;i++) vals[i] = 0;
    }
    unsigned short* d = (unsigned short*)dst + (long)l*212992 + (768+rowo)*256 + kbase;
    #pragma unroll
    for(int i=0;i<8;i++) d[i] = vals[i];
    return;
  }
  const float* src; __hip_bfloat16* d; int K, N, tile;
  if(bid < 384){
    int l = bid / 192, rem = bid % 192, mat = rem >> 6; tile = rem & 63;
    src = (mat==0 ? Wq : (mat==1 ? Wk : Wv)) + l*65536;
    d = dst + (long)l*212992 + mat*65536;
    K = 256; N = 256;
  } else if(bid < 512){
    int b2 = bid - 384; int l = b2 >> 6; tile = b2 & 63;
    src = Wo + l*65536; d = dst + OFF_WOT + l*65536; K = 256; N = 256;
  } else if(bid < 1040){
    int b2 = bid - 528; int l = b2 >> 8; tile = b2 & 255;
    src = f1w + l*262144; d = dst + OFF_F1T + l*262144; K = 256; N = 1024;
  } else {
    int b2 = bid - 1040; int l = b2 >> 8; tile = b2 & 255;
    src = f2w + l*262144; d = dst + OFF_F2T + l*262144; K = 1024; N = 256;
  }
  int ntn = N >> 5;
  int tk = tile / ntn, tn = tile - tk*ntn;
  int k0 = tk*32, n0 = tn*32;
  {
    int rr = t >> 3, cc = (t & 7) * 4;
    float4 v = *(const float4*)&src[(long)(k0+rr)*N + n0 + cc];
    sh[rr][cc]=v.x; sh[rr][cc+1]=v.y; sh[rr][cc+2]=v.z; sh[rr][cc+3]=v.w;
  }
  __syncthreads();
  int nn = t >> 3, kk = (t & 7) * 4;
  ushort4 o;
  o.x = f2bf(sh[kk+0][nn]);
  o.y = f2bf(sh[kk+1][nn]);
  o.z = f2bf(sh[kk+2][nn]);
  o.w = f2bf(sh[kk+3][nn]);
  *(ushort4*)&((unsigned short*)d)[(long)(n0+nn)*K + k0 + kk] = o;
}

__global__ __launch_bounds__(256) void embed_ln_kernel(
    const int* __restrict__ ids, const float* __restrict__ tok, const float* __restrict__ pos,
    const float* __restrict__ g, const float* __restrict__ bt,
    float* __restrict__ h, __hip_bfloat16* __restrict__ hb){
  int t = threadIdx.x;
  int lane = t & 63;
  int row = blockIdx.x*4 + (t >> 6);
  int n = row & (NSEQ-1);
  int id = ids[row];
  float4 vv = ((const float4*)tok)[(long)id*64 + lane];
  float4 pv = ((const float4*)pos)[n*64 + lane];
  vv.x += pv.x; vv.y += pv.y; vv.z += pv.z; vv.w += pv.w;
  float s  = vv.x+vv.y+vv.z+vv.w;
  float s2 = vv.x*vv.x+vv.y*vv.y+vv.z*vv.z+vv.w*vv.w;
  #pragma unroll
  for(int off=1; off<64; off<<=1){ s += __shfl_xor(s, off); s2 += __shfl_xor(s2, off); }
  float mean = s*(1.f/DV);
  float var = fmaxf(s2*(1.f/DV) - mean*mean, 0.f);
  float inv = rsqrtf(var + 1e-5f);
  float4 gv = ((const float4*)g)[lane];
  float4 bv = ((const float4*)bt)[lane];
  float4 o;
  o.x=(vv.x-mean)*inv*gv.x+bv.x; o.y=(vv.y-mean)*inv*gv.y+bv.y;
  o.z=(vv.z-mean)*inv*gv.z+bv.z; o.w=(vv.w-mean)*inv*gv.w+bv.w;
  ((float4*)h)[row*64 + lane] = o;
  ushort4 ob; ob.x=f2bf(o.x); ob.y=f2bf(o.y); ob.z=f2bf(o.z); ob.w=f2bf(o.w);
  *(ushort4*)&hb[row*DV + lane*4] = ob;
}

// ==================== device unit functions (mega kernel stages) ====================

// 64x64 tile, BK=128 double-buffered, 4 waves (2x2), FM=FN=2. OUT bf16.
template<int ACT, int PHASE>
__device__ void gemm64_unit(char* SM, int u, int gx,
    const unsigned short* A, const unsigned short* Bt, const float* bias,
    unsigned short* Cout, int N, int ldc, int K,
    const float* pb, float* cph, float* sph){
  auto As = (short(*)[64][136])SM;
  auto Bs = (short(*)[64][136])(SM + 34816);
  int bx = u % gx, by = u / gx;
  int tm = bx*64, tn = by*64;
  int t = threadIdx.x;
  int lane = t & 63, w = t >> 6;
  int wm = w >> 1, wn = w & 1;
  int lr = lane & 15, lg = lane >> 4;
  f32x4 acc[2][2] = {};
  const short* gA = (const short*)A;
  const short* gB = (const short*)Bt;
  int ra = t >> 2, ca = t & 3;
  short8v ar[4], br[4];
#define LOADC64(K0) { const short* pa = &gA[(long)(tm+ra)*K + (K0)]; \
    _Pragma("unroll") for(int j=0;j<4;j++) ar[j] = *(const short8v*)&pa[(ca+4*j)*8]; \
    const short* pbp = &gB[(long)(tn+ra)*K + (K0)]; \
    _Pragma("unroll") for(int j=0;j<4;j++) br[j] = *(const short8v*)&pbp[(ca+4*j)*8]; }
#define STOREC64(BUF) { _Pragma("unroll") for(int j=0;j<4;j++) *(short8v*)&As[BUF][ra][(ca+4*j)*8] = ar[j]; \
    _Pragma("unroll") for(int j=0;j<4;j++) *(short8v*)&Bs[BUF][ra][(ca+4*j)*8] = br[j]; }
  int nch = K >> 7;
  LOADC64(0);
  __syncthreads();           // guard LDS reuse across units/stages
  STOREC64(0);
  if(nch > 1) LOADC64(128);
  __syncthreads();
  for(int c=0; c<nch; c++){
    int cur = c & 1;
    #pragma unroll
    for(int ks=0; ks<4; ks++){
      short8v af[2], bf[2];
      #pragma unroll
      for(int i=0;i<2;i++) af[i] = *(const short8v*)&As[cur][wm*32 + i*16 + lr][ks*32 + lg*8];
      #pragma unroll
      for(int j=0;j<2;j++) bf[j] = *(const short8v*)&Bs[cur][wn*32 + j*16 + lr][ks*32 + lg*8];
      #pragma unroll
      for(int i=0;i<2;i++)
        #pragma unroll
        for(int j=0;j<2;j++)
          acc[i][j] = __builtin_amdgcn_mfma_f32_16x16x32_bf16(af[i], bf[j], acc[i][j], 0,0,0);
    }
    if(c+1 < nch){
      STOREC64(cur^1);
      if(c+2 < nch) LOADC64((c+2)*128);
    }
    __syncthreads();
  }
#undef LOADC64
#undef STOREC64
  if(PHASE && tn >= N - 64){
    #pragma unroll
    for(int fn=0; fn<2; fn++){
      int colr = wn*32 + fn*16 + lr;
      if(colr < 8){
        float bb = pb[colr];
        #pragma unroll
        for(int fm=0; fm<2; fm++){
          int row0 = tm + wm*32 + fm*16 + lg*4;
          #pragma unroll
          for(int r2=0; r2<4; r2++){
            float ph = acc[fm][fn][r2] + bb;
            float sv, cv;
            __sincosf(ph, &sv, &cv);
            int row = row0 + r2;
            int b = row >> 10, n = row & 1023;
            int idx = (b*HHEADS + colr)*NSEQ + n;
            cph[idx] = cv; sph[idx] = sv;
          }
        }
      }
    }
    return;
  }
  #pragma unroll
  for(int fn=0; fn<2; fn++){
    int col = tn + wn*32 + fn*16 + lr;
    float bs = bias ? bias[col] : 0.f;
    #pragma unroll
    for(int fm=0; fm<2; fm++){
      int row0 = tm + wm*32 + fm*16 + lg*4;
      #pragma unroll
      for(int r2=0; r2<4; r2++){
        float xx = acc[fm][fn][r2] + bs;
        if(ACT == 1) xx = 0.5f*xx*(1.f + erff(xx*0.70710678118654752f));
        Cout[(long)(row0+r2)*ldc + col] = f2bf(xx);
      }
    }
  }
}

// 32x32 tile, K=1024, BK=128 double-buffered, 4 waves (2x2), FM=FN=1. OUT f32 (FF2).
__device__ void gemm32_unit(char* SM, int u,
    const unsigned short* A, const unsigned short* Bt, const float* bias, float* Cout){
  auto As = (short(*)[32][136])SM;
  auto Bs = (short(*)[32][136])(SM + 17408);
  const int K = 1024, ldc = 256;
  int bx = u % 64, by = u / 64;
  int tm = bx*32, tn = by*32;
  int t = threadIdx.x;
  int lane = t & 63, w = t >> 6;
  int wm = w >> 1, wn = w & 1;
  int lr = lane & 15, lg = lane >> 4;
  f32x4 acc = {0.f,0.f,0.f,0.f};
  const short* gA = (const short*)A;
  const short* gB = (const short*)Bt;
  int ra = t >> 3, ca = t & 7;
  short8v ar[2], br[2];
#define LOADC32(K0) { const short* pa = &gA[(long)(tm+ra)*K + (K0)]; \
    ar[0] = *(const short8v*)&pa[ca*8]; ar[1] = *(const short8v*)&pa[(ca+8)*8]; \
    const short* pbp = &gB[(long)(tn+ra)*K + (K0)]; \
    br[0] = *(const short8v*)&pbp[ca*8]; br[1] = *(const short8v*)&pbp[(ca+8)*8]; }
#define STOREC32(BUF) { *(short8v*)&As[BUF][ra][ca*8] = ar[0]; *(short8v*)&As[BUF][ra][(ca+8)*8] = ar[1]; \
    *(short8v*)&Bs[BUF][ra][ca*8] = br[0]; *(short8v*)&Bs[BUF][ra][(ca+8)*8] = br[1]; }
  LOADC32(0);
  __syncthreads();
  STOREC32(0);
  LOADC32(128);
  __syncthreads();
  for(int c=0; c<8; c++){
    int cur = c & 1;
    #pragma unroll
    for(int ks=0; ks<4; ks++){
      short8v af = *(const short8v*)&As[cur][wm*16 + lr][ks*32 + lg*8];
      short8v bf = *(const short8v*)&Bs[cur][wn*16 + lr][ks*32 + lg*8];
      acc = __builtin_amdgcn_mfma_f32_16x16x32_bf16(af, bf, acc, 0,0,0);
    }
    if(c+1 < 8){
      STOREC32(cur^1);
      if(c+2 < 8) LOADC32((c+2)*128);
    }
    __syncthreads();
  }
#undef LOADC32
#undef STOREC32
  int col = tn + wn*16 + lr;
  float bs = bias[col];
  int row0 = tm + wm*16 + lg*4;
  #pragma unroll
  for(int r2=0; r2<4; r2++)
    Cout[(long)(row0+r2)*ldc + col] = acc[r2] + bs;
}

// attention unit: split-K x4, static softmax, double-buffered (R11 body).
__device__ void attn_unit(char* SM, int u,
    const unsigned short* qkv, const float* cph, const float* sph,
    unsigned short* po, float* ml){
  auto K2 = (short(*)[64][104])SM;              // [2][64][104]
  auto V2 = (short(*)[32][72])(SM + 26624);     // [2][32][72]
  auto Pp = (short(*)[16][72])(SM + 35840);     // [4][16][72]
  int bh = u >> 6;
  int qt = (u >> 2) & 15;
  int ks = u & 3;
  int b = bh >> 3, hh = bh & 7;
  int t = threadIdx.x;
  int lane = t & 63, w = t >> 6;
  int lr = lane & 15, lg = lane >> 4;
  int q0w = qt*64 + w*16;

  const unsigned short* qrow = qkv + ((long)(b*NSEQ + q0w + lr))*768 + hh*32 + lg*8;
  short8v qraw = *(const short8v*)qrow;
  float ci = cph[bh*NSEQ + q0w + lr];
  float si = sph[bh*NSEQ + q0w + lr];
  short8v qf0, qf1, qf2;
  #pragma unroll
  for(int i=0;i<8;i++){
    float x = bfbits2f((unsigned short)qraw[i]) * (0.5f*QKSCALE);
    qf0[i] = (short)f2bf(x);
    qf1[i] = (short)f2bf(x*ci);
    qf2[i] = (short)f2bf(x*si);
  }

  int srow = t >> 2, sdc = (t & 3) * 8;
  int j0b = ks*4;
  short8v kv, vvr; float cj, sj;
#define LOADT(J) { long rg = (long)(b*NSEQ + (J)*64 + srow)*768; \
    kv  = *(const short8v*)(qkv + rg + 256 + hh*32 + sdc); \
    vvr = *(const short8v*)(qkv + rg + 512 + hh*32 + sdc); \
    cj = cph[bh*NSEQ + (J)*64 + srow]; sj = sph[bh*NSEQ + (J)*64 + srow]; }
#define STORET(BUF) { short8v kc, ksv; \
    _Pragma("unroll") for(int i=0;i<8;i++){ float x = bfbits2f((unsigned short)kv[i]); \
      kc[i] = (short)f2bf(x*cj); ksv[i] = (short)f2bf(x*sj); } \
    *(short8v*)&K2[BUF][srow][sdc]    = kv; \
    *(short8v*)&K2[BUF][srow][32+sdc] = kc; \
    *(short8v*)&K2[BUF][srow][64+sdc] = ksv; \
    _Pragma("unroll") for(int i=0;i<8;i++) V2[BUF][sdc+i][srow] = vvr[i]; }

  float l = 0.f;
  f32x4 acc[2] = {};

  LOADT(j0b);
  __syncthreads();           // guard LDS reuse across units/stages
  STORET(0);
  LOADT(j0b+1);
  __syncthreads();
  for(int j=0; j<4; j++){
    int cur = j & 1;
    f32x4 st[4];
    #pragma unroll
    for(int kt=0; kt<4; kt++){
      short8v a0 = *(const short8v*)&K2[cur][kt*16+lr][lg*8];
      short8v a1 = *(const short8v*)&K2[cur][kt*16+lr][32+lg*8];
      short8v a2 = *(const short8v*)&K2[cur][kt*16+lr][64+lg*8];
      f32x4 z = {0.f,0.f,0.f,0.f};
      z = __builtin_amdgcn_mfma_f32_16x16x32_bf16(a0, qf0, z, 0,0,0);
      z = __builtin_amdgcn_mfma_f32_16x16x32_bf16(a1, qf1, z, 0,0,0);
      z = __builtin_amdgcn_mfma_f32_16x16x32_bf16(a2, qf2, z, 0,0,0);
      st[kt] = z;
    }
    float ls = 0.f;
    #pragma unroll
    for(int kt=0; kt<4; kt++){
      float p0 = __expf(st[kt][0]);
      float p1 = __expf(st[kt][1]);
      float p2 = __expf(st[kt][2]);
      float p3 = __expf(st[kt][3]);
      ls += (p0+p1)+(p2+p3);
      unsigned int w0 = (unsigned)f2bf(p0) | ((unsigned)f2bf(p1)<<16);
      unsigned int w1 = (unsigned)f2bf(p2) | ((unsigned)f2bf(p3)<<16);
      unsigned int* pp = (unsigned int*)&Pp[w][lr][kt*16 + lg*4];
      pp[0] = w0; pp[1] = w1;
    }
    ls += __shfl_xor(ls, 16);
    ls += __shfl_xor(ls, 32);
    l += ls;
    #pragma unroll
    for(int kk=0; kk<2; kk++){
      short8v pa  = *(const short8v*)&Pp[w][lr][kk*32 + lg*8];
      short8v vf0 = *(const short8v*)&V2[cur][lr][kk*32 + lg*8];
      short8v vf1 = *(const short8v*)&V2[cur][16+lr][kk*32 + lg*8];
      acc[0] = __builtin_amdgcn_mfma_f32_16x16x32_bf16(pa, vf0, acc[0], 0,0,0);
      acc[1] = __builtin_amdgcn_mfma_f32_16x16x32_bf16(pa, vf1, acc[1], 0,0,0);
    }
    if(j < 3){
      STORET(cur^1);
      if(j < 2) LOADT(j0b+j+2);
    }
    __syncthreads();
  }
#undef LOADT
#undef STORET
  if(lane < 16){
    ml[((long)(ks*16+bh))*NSEQ + q0w + lr] = l;
  }
  #pragma unroll
  for(int dt=0; dt<2; dt++)
    #pragma unroll
    for(int r=0;r<4;r++){
      int row = q0w + lg*4 + r;
      po[(((long)(ks*16+bh))*NSEQ + row)*32 + dt*16 + lr] = f2bf(acc[dt][r]);
    }
}

// wo_ln unit: combine(x4) + @Wo + residual + LN1, 8-row stripes (R11 body).
__device__ void wo_ln_unit(char* SM, int u,
    const unsigned short* po, const float* ml,
    const unsigned short* Bt, const float* hres,
    const float* lng, const float* lnb,
    float* h1, unsigned short* hb1){
  auto As = (short(*)[264])SM;                  // [16][264]
  auto Bs = (short(*)[264])(SM + 8448);         // [64][264]
  auto Co = (float(*)[260])(SM + 42240);        // [8][260]
  int tm = u*8;
  int t = threadIdx.x;
  int lane = t & 63, w = t >> 6;
  int lr = lane & 15, lg = lane >> 4;
  {
    int r = t >> 5;
    int c8 = (t & 31) * 8;
    int R = tm + r; int b = R >> 10, q = R & 1023;
    int bh = b*HHEADS + (c8 >> 5);
    long mlb = (long)bh*NSEQ + q;
    float lsum = ml[mlb] + ml[mlb + 16*NSEQ] + ml[mlb + 32*NSEQ] + ml[mlb + 48*NSEQ];
    float inv = 1.f/lsum;
    long pob = ((long)bh*NSEQ + q)*32 + (c8 & 31);
    short8v a0 = *(const short8v*)&po[pob];
    short8v a1 = *(const short8v*)&po[pob + (long)16*NSEQ*32];
    short8v a2 = *(const short8v*)&po[pob + (long)32*NSEQ*32];
    short8v a3 = *(const short8v*)&po[pob + (long)48*NSEQ*32];
    short8v o;
    #pragma unroll
    for(int k=0;k<8;k++)
      o[k] = (short)f2bf((bfbits2f((unsigned short)a0[k]) + bfbits2f((unsigned short)a1[k])
                        + bfbits2f((unsigned short)a2[k]) + bfbits2f((unsigned short)a3[k]))*inv);
    *(short8v*)&As[r][c8] = o;
    short8v z = {0,0,0,0,0,0,0,0};
    *(short8v*)&As[8+r][c8] = z;
  }
  const short* gB = (const short*)Bt;
  int rb = t >> 2, cb = t & 3;
  {
    const short* pbp = &gB[(long)rb*256];
    #pragma unroll
    for(int j=0;j<8;j++) *(short8v*)&Bs[rb][(cb+4*j)*8] = *(const short8v*)&pbp[(cb+4*j)*8];
  }
  __syncthreads();
  f32x4 acc[4] = {};
  for(int ct=0; ct<4; ct++){
    #pragma unroll
    for(int ksx=0; ksx<8; ksx++){
      short8v af = *(const short8v*)&As[lr][ksx*32 + lg*8];
      short8v bf = *(const short8v*)&Bs[w*16+lr][ksx*32 + lg*8];
      acc[ct] = __builtin_amdgcn_mfma_f32_16x16x32_bf16(af, bf, acc[ct], 0,0,0);
    }
    if(ct < 3){
      __syncthreads();
      const short* pbp = &gB[(long)((ct+1)*64 + rb)*256];
      #pragma unroll
      for(int j=0;j<8;j++) *(short8v*)&Bs[rb][(cb+4*j)*8] = *(const short8v*)&pbp[(cb+4*j)*8];
      __syncthreads();
    }
  }
  #pragma unroll
  for(int ct=0; ct<4; ct++)
    #pragma unroll
    for(int r2=0; r2<4; r2++){
      int rw = lg*4 + r2;
      if(rw < 8) Co[rw][ct*64 + w*16 + lr] = acc[ct][r2];
    }
  __syncthreads();
  {
    int r = t >> 5;
    int c8 = (t & 31) * 8;
    int R = tm + r;
    float v[8];
    float s = 0.f, s2 = 0.f;
    const float* hr = hres + (long)R*DV + c8;
    #pragma unroll
    for(int i=0;i<2;i++){
      float4 hv = *(const float4*)&hr[4*i];
      float x0 = Co[r][c8+4*i]   + hv.x;
      float x1 = Co[r][c8+4*i+1] + hv.y;
      float x2 = Co[r][c8+4*i+2] + hv.z;
      float x3 = Co[r][c8+4*i+3] + hv.w;
      v[4*i]=x0; v[4*i+1]=x1; v[4*i+2]=x2; v[4*i+3]=x3;
      s += x0+x1+x2+x3;
      s2 += x0*x0+x1*x1+x2*x2+x3*x3;
    }
    #pragma unroll
    for(int off=1; off<32; off<<=1){ s += __shfl_xor(s, off); s2 += __shfl_xor(s2, off); }
    float mean = s*(1.f/DV);
    float var = fmaxf(s2*(1.f/DV) - mean*mean, 0.f);
    float invs = rsqrtf(var + 1e-5f);
    #pragma unroll
    for(int i=0;i<2;i++){
      int col = c8 + 4*i;
      float4 gv = *(const float4*)&lng[col];
      float4 bv = *(const float4*)&lnb[col];
      float o0 = (v[4*i+0]-mean)*invs*gv.x + bv.x;
      float o1 = (v[4*i+1]-mean)*invs*gv.y + bv.y;
      float o2 = (v[4*i+2]-mean)*invs*gv.z + bv.z;
      float o3 = (v[4*i+3]-mean)*invs*gv.w + bv.w;
      *(float4*)&h1[(long)R*DV + col] = make_float4(o0,o1,o2,o3);
      ushort4 ob; ob.x=f2bf(o0); ob.y=f2bf(o1); ob.z=f2bf(o2); ob.w=f2bf(o3);
      *(ushort4*)&hb1[(long)R*DV + col] = ob;
    }
  }
}

// ln2 unit: residual + LN, 4 rows.
__device__ void ln2_unit(int u, const float* x, const float* r,
    float* out, unsigned short* outb, const float* g, const float* bt){
  int t = threadIdx.x;
  int lane = t & 63;
  int row = u*4 + (t >> 6);
  float4 vv = ((const float4*)x)[row*64 + lane];
  float4 rv = ((const float4*)r)[row*64 + lane];
  vv.x += rv.x; vv.y += rv.y; vv.z += rv.z; vv.w += rv.w;
  float s  = vv.x+vv.y+vv.z+vv.w;
  float s2 = vv.x*vv.x+vv.y*vv.y+vv.z*vv.z+vv.w*vv.w;
  #pragma unroll
  for(int off=1; off<64; off<<=1){ s += __shfl_xor(s, off); s2 += __shfl_xor(s2, off); }
  float mean = s*(1.f/DV);
  float var = fmaxf(s2*(1.f/DV) - mean*mean, 0.f);
  float inv = rsqrtf(var + 1e-5f);
  float4 gv = ((const float4*)g)[lane];
  float4 bv = ((const float4*)bt)[lane];
  float4 o;
  o.x=(vv.x-mean)*inv*gv.x+bv.x; o.y=(vv.y-mean)*inv*gv.y+bv.y;
  o.z=(vv.z-mean)*inv*gv.z+bv.z; o.w=(vv.w-mean)*inv*gv.w+bv.w;
  ((float4*)out)[row*64 + lane] = o;
  ushort4 ob; ob.x=f2bf(o.x); ob.y=f2bf(o.y); ob.z=f2bf(o.z); ob.w=f2bf(o.w);
  *(ushort4*)&outb[row*DV + lane*4] = ob;
}

// final: LN2 -> outLN -> column partial sums, 8-row stripes (256 units).
__device__ void final_unit(char* SM, int u,
    const float* x, const float* r,
    const float* g2, const float* b2,
    const float* og, const float* ob2,
    float* part){
  auto ws2 = (float(*)[260])SM;  // [8][260]
  int t = threadIdx.x;
  int lrow = t >> 5;
  int row = u*8 + lrow;
  int c0 = (t & 31) * 8;
  float v[8];
  float s=0.f, s2=0.f;
  const float* xr = x + (long)row*DV + c0;
  const float* rr = r + (long)row*DV + c0;
  #pragma unroll
  for(int i=0;i<2;i++){
    float4 xv = *(const float4*)&xr[4*i];
    float4 rv = *(const float4*)&rr[4*i];
    xv.x+=rv.x; xv.y+=rv.y; xv.z+=rv.z; xv.w+=rv.w;
    v[4*i]=xv.x; v[4*i+1]=xv.y; v[4*i+2]=xv.z; v[4*i+3]=xv.w;
    s += xv.x+xv.y+xv.z+xv.w;
    s2 += xv.x*xv.x+xv.y*xv.y+xv.z*xv.z+xv.w*xv.w;
  }
  #pragma unroll
  for(int off=1; off<32; off<<=1){ s += __shfl_xor(s, off); s2 += __shfl_xor(s2, off); }
  float mean = s*(1.f/DV);
  float var = fmaxf(s2*(1.f/DV)-mean*mean, 0.f);
  float inv = rsqrtf(var + 1e-5f);
  float s_=0.f, s2_=0.f;
  #pragma unroll
  for(int i=0;i<8;i++){
    int col = c0 + i;
    float o = (v[i]-mean)*inv*g2[col] + b2[col];
    v[i] = o;
    s_ += o; s2_ += o*o;
  }
  #pragma unroll
  for(int off=1; off<32; off<<=1){ s_ += __shfl_xor(s_, off); s2_ += __shfl_xor(s2_, off); }
  float mean2 = s_*(1.f/DV);
  float var2 = fmaxf(s2_*(1.f/DV)-mean2*mean2, 0.f);
  float inv2 = rsqrtf(var2 + 1e-5f);
  __syncthreads();   // guard: prior stage LDS reads done before ws2 writes
  #pragma unroll
  for(int i=0;i<8;i++){
    int col = c0 + i;
    ws2[lrow][col] = (v[i]-mean2)*inv2*og[col] + ob2[col];
  }
  __syncthreads();
  float accv = 0.f;
  #pragma unroll
  for(int rr2=0; rr2<8; rr2++) accv += ws2[rr2][t];
  part[u*DV + t] = accv;
}

// head: reduce 128 partials/batch + matvec, 125 units x 256 cols.
__device__ void head_unit(char* SM, int u,
    const float* part, const float* W, const float* hb, float* out){
  auto pooled = (float(*)[256])SM;
  int t = threadIdx.x;
  {
    float a0 = 0.f, a1 = 0.f;
    #pragma unroll 8
    for(int k=0;k<128;k++){ a0 += part[k*DV + t]; a1 += part[(128+k)*DV + t]; }
    pooled[0][t] = a0 * (1.f/NSEQ);
    pooled[1][t] = a1 * (1.f/NSEQ);
  }
  __syncthreads();
  int vcol = u*256 + t;
  float x0 = 0.f, x1 = 0.f;
  #pragma unroll 8
  for(int d=0; d<DV; d++){
    float wv = W[(long)d*VV + vcol];
    x0 += pooled[0][d]*wv;
    x1 += pooled[1][d]*wv;
  }
  float bb = hb[vcol];
  out[vcol] = x0 + bb;
  out[VV + vcol] = x1 + bb;
}

// ==================== mega kernel (cooperative) ====================

struct MegaParams {
  const unsigned short* wqkvp;
  const unsigned short* wot;
  const unsigned short* f1t;
  const unsigned short* f2t;
  unsigned short* qkv;
  unsigned short* po;
  unsigned short* ff;
  unsigned short* hb;
  unsigned short* hb1;
  float* h; float* h1; float* s_ff; float* mlb;
  float* cphb; float* sphb; float* part; float* outp;
  const float* pp_b; const float* f1_b; const float* f2_b;
  const float* ln1_g; const float* ln1_b;
  const float* ln2_g; const float* ln2_b;
  const float* on_g; const float* on_b;
  const float* head_w; const float* head_b;
};

__global__ __launch_bounds__(256) void mega_kernel(MegaParams p){
  __shared__ __align__(16) char SM[69632];
  cg::grid_group grid = cg::this_grid();
  int bid = blockIdx.x;
  for(int it=0; it<4; it++){
    int l = it & 1;
    // A: QKV + phase (416 units)
    for(int u=bid; u<416; u+=256)
      gemm64_unit<0,1>(SM, u, 32, p.hb, p.wqkvp + (long)l*212992, nullptr,
                       p.qkv, 832, 768, 256, p.pp_b + l*HHEADS, p.cphb, p.sphb);
    __threadfence(); grid.sync();
    // B: attention (1024 units)
    for(int u=bid; u<1024; u+=256)
      attn_unit(SM, u, p.qkv, p.cphb, p.sphb, p.po, p.mlb);
    __threadfence(); grid.sync();
    // C: combine + Wo + residual + LN1 (256 units)
    wo_ln_unit(SM, bid, p.po, p.mlb, p.wot + (long)l*65536, p.h,
               p.ln1_g + l*DV, p.ln1_b + l*DV, p.h1, p.hb1);
    __threadfence(); grid.sync();
    // D: FF1 + GELU (512 units)
    for(int u=bid; u<512; u+=256)
      gemm64_unit<1,0>(SM, u, 32, p.hb1, p.f1t + (long)l*262144, p.f1_b + l*1024,
                       p.ff, 1024, 1024, 256, nullptr, nullptr, nullptr);
    __threadfence(); grid.sync();
    // E: FF2 (512 units)
    for(int u=bid; u<512; u+=256)
      gemm32_unit(SM, u, p.ff, p.f2t + (long)l*262144, p.f2_b + l*DV, p.s_ff);
    __threadfence(); grid.sync();
    // F: ln2 (512 units), skipped on last iteration
    if(it < 3){
      for(int u=bid; u<512; u+=256)
        ln2_unit(u, p.s_ff, p.h1, p.h, p.hb, p.ln2_g + l*DV, p.ln2_b + l*DV);
    }
    __threadfence(); grid.sync();
  }
  final_unit(SM, bid, p.s_ff, p.h1, p.ln2_g + DV, p.ln2_b + DV, p.on_g, p.on_b, p.part);
  __threadfence(); grid.sync();
  if(bid < 125)
    head_unit(SM, bid, p.part, p.head_w, p.head_b, p.outp);
}

// ==================== fallback kernels (R11, used if coop launch unavailable) ====================

__global__ __launch_bounds__(256) void ln_res_kernel(
    const float* __restrict__ x, const float* __restrict__ r,
    float* __restrict__ out, __hip_bfloat16* __restrict__ outb,
    const float* __restrict__ g, const float* __restrict__ bt){
  ln2_unit(blockIdx.x, x, r, out, (unsigned short*)outb, g, bt);
}

__global__ __launch_bounds__(256) void qkv_gemm_kernel(
    const __hip_bfloat16* A, const __hip_bfloat16* Bt,
    __hip_bfloat16* Cout, const float* pb, float* cph, float* sph){
  __shared__ __align__(16) char SM[69632];
  gemm64_unit<0,1>(SM, blockIdx.x, 32, (const unsigned short*)A, (const unsigned short*)Bt,
                   nullptr, (unsigned short*)Cout, 832, 768, 256, pb, cph, sph);
}

__global__ __launch_bounds__(256) void ff1_gemm_kernel(
    const __hip_bfloat16* A, const __hip_bfloat16* Bt, const float* bias,
    __hip_bfloat16* Cout){
  __shared__ __align__(16) char SM[69632];
  gemm64_unit<1,0>(SM, blockIdx.x, 32, (const unsigned short*)A, (const unsigned short*)Bt,
                   bias, (unsigned short*)Cout, 1024, 1024, 256, nullptr, nullptr, nullptr);
}

__global__ __launch_bounds__(256) void ff2_gemm_kernel(
    const __hip_bfloat16* A, const __hip_bfloat16* Bt, const float* bias, float* Cout){
  __shared__ __align__(16) char SM[34816];
  gemm32_unit(SM, blockIdx.x, (const unsigned short*)A, (const unsigned short*)Bt, bias, Cout);
}

__global__ __launch_bounds__(256) void attn_kernel_fb(
    const __hip_bfloat16* qkv, const float* cph, const float* sph,
    __hip_bfloat16* po, float* ml){
  __shared__ __align__(16) char SM[45056];
  attn_unit(SM, blockIdx.x, (const unsigned short*)qkv, cph, sph, (unsigned short*)po, ml);
}

__global__ __launch_bounds__(256) void wo_ln_kernel_fb(
    const __hip_bfloat16* po, const float* ml, const __hip_bfloat16* Bt,
    const float* hres, const float* lng, const float* lnb,
    float* h1, __hip_bfloat16* hb1){
  __shared__ __align__(16) char SM[50560];
  wo_ln_unit(SM, blockIdx.x, (const unsigned short*)po, ml, (const unsigned short*)Bt,
             hres, lng, lnb, h1, (unsigned short*)hb1);
}

__global__ __launch_bounds__(256) void final_pool_kernel_fb(
    const float* x, const float* r, const float* g2, const float* b2,
    const float* og, const float* ob, float* part){
  __shared__ __align__(16) char SM[8320];
  final_unit(SM, blockIdx.x, x, r, g2, b2, og, ob, part);
}

__global__ __launch_bounds__(256) void head_kernel_fb(
    const float* part, const float* W, const float* hb, float* out){
  __shared__ __align__(16) char SM[2048];
  head_unit(SM, blockIdx.x, part, W, hb, out);
}

// ==================== launcher ====================

extern "C" void kernel_launch(void* const* d_in, const int* in_sizes, int n_in,
                              void* d_out, int out_size, void* d_ws, size_t ws_size,
                              hipStream_t stream){
  const int*   ids   = (const int*)  d_in[0];
  const float* tok   = (const float*)d_in[1];
  const float* pos   = (const float*)d_in[2];
  const float* en_g  = (const float*)d_in[3];
  const float* en_b  = (const float*)d_in[4];
  const float* Wq    = (const float*)d_in[7];
  const float* Wk    = (const float*)d_in[8];
  const float* Wv    = (const float*)d_in[9];
  const float* Wo    = (const float*)d_in[10];
  const float* pp_w  = (const float*)d_in[11];
  const float* pp_b  = (const float*)d_in[12];
  const float* f1_w  = (const float*)d_in[13];
  const float* f1_b  = (const float*)d_in[14];
  const float* f2_w  = (const float*)d_in[15];
  const float* f2_b  = (const float*)d_in[16];
  const float* ln1_g = (const float*)d_in[17];
  const float* ln1_b = (const float*)d_in[18];
  const float* ln2_g = (const float*)d_in[19];
  const float* ln2_b = (const float*)d_in[20];
  const float* on_g  = (const float*)d_in[23];
  const float* on_b  = (const float*)d_in[24];
  const float* head_w= (const float*)d_in[25];
  const float* head_b= (const float*)d_in[26];
  float* out = (float*)d_out;

  char* wsb = (char*)d_ws;
  float* h    = (float*)(wsb);
  __hip_bfloat16* hb  = (__hip_bfloat16*)(wsb + (2u<<20));
  float* h1   = (float*)(wsb + (3u<<20));
  __hip_bfloat16* hb1 = (__hip_bfloat16*)(wsb + (5u<<20));
  __hip_bfloat16* qkv = (__hip_bfloat16*)(wsb + (6u<<20));
  __hip_bfloat16* po  = (__hip_bfloat16*)(wsb + (9u<<20));
  float* mlb  = (float*)(wsb + (13u<<20));
  __hip_bfloat16* ff  = (__hip_bfloat16*)(wsb + (14u<<20));
  float* s_ff = (float*)(wsb + (18u<<20));
  float* cphb = (float*)(wsb + (20u<<20));
  float* sphb = cphb + 16384;
  float* part = (float*)(wsb + (20u<<20) + (128u<<10));
  __hip_bfloat16* wt = (__hip_bfloat16*)(wsb + (20u<<20) + (512u<<10));
  __hip_bfloat16* wqkvp = wt + OFF_WQKVP;
  __hip_bfloat16* wot   = wt + OFF_WOT;
  __hip_bfloat16* f1t   = wt + OFF_F1T;
  __hip_bfloat16* f2t   = wt + OFF_F2T;

  transpose_cvt_all<<<1552, 256, 0, stream>>>(Wq, Wk, Wv, Wo, pp_w, f1_w, f2_w, wt);
  embed_ln_kernel<<<512, 256, 0, stream>>>(ids, tok, pos, en_g, en_b, h, hb);

  MegaParams p;
  p.wqkvp = (const unsigned short*)wqkvp;
  p.wot   = (const unsigned short*)wot;
  p.f1t   = (const unsigned short*)f1t;
  p.f2t   = (const unsigned short*)f2t;
  p.qkv = (unsigned short*)qkv;
  p.po  = (unsigned short*)po;
  p.ff  = (unsigned short*)ff;
  p.hb  = (unsigned short*)hb;
  p.hb1 = (unsigned short*)hb1;
  p.h = h; p.h1 = h1; p.s_ff = s_ff; p.mlb = mlb;
  p.cphb = cphb; p.sphb = sphb; p.part = part; p.outp = out;
  p.pp_b = pp_b; p.f1_b = f1_b; p.f2_b = f2_b;
  p.ln1_g = ln1_g; p.ln1_b = ln1_b;
  p.ln2_g = ln2_g; p.ln2_b = ln2_b;
  p.on_g = on_g; p.on_b = on_b;
  p.head_w = head_w; p.head_b = head_b;

  bool coop_done = false;
  int nb = 0;
  if(hipOccupancyMaxActiveBlocksPerMultiprocessor(&nb, mega_kernel, 256, 0) == hipSuccess
     && nb >= 1){
    void* args[] = { &p };
    if(hipLaunchCooperativeKernel(mega_kernel, dim3(256), dim3(256), args, 0, stream)
       == hipSuccess)
      coop_done = true;
  }
  if(!coop_done){
    // fallback: R11-style dispatch sequence using the same unit bodies
    for(int it=0; it<4; it++){
      int l = it & 1;
      qkv_gemm_kernel<<<416, 256, 0, stream>>>(hb, wqkvp + (long)l*212992, qkv,
                                               pp_b + l*HHEADS, cphb, sphb);
      attn_kernel_fb<<<1024, 256, 0, stream>>>(qkv, cphb, sphb, po, mlb);
      wo_ln_kernel_fb<<<256, 256, 0, stream>>>(po, mlb, wot + l*65536, h,
                                               ln1_g + l*DV, ln1_b + l*DV, h1, hb1);
      ff1_gemm_kernel<<<512, 256, 0, stream>>>(hb1, f1t + (long)l*262144, f1_b + l*1024, ff);
      ff2_gemm_kernel<<<512, 256, 0, stream>>>(ff, f2t + (long)l*262144, f2_b + l*DV, s_ff);
      if(it < 3)
        ln_res_kernel<<<512, 256, 0, stream>>>(s_ff, h1, h, hb, ln2_g + l*DV, ln2_b + l*DV);
    }
    final_pool_kernel_fb<<<256, 256, 0, stream>>>(s_ff, h1, ln2_g + DV, ln2_b + DV,
                                                  on_g, on_b, part);
    head_kernel_fb<<<125, 256, 0, stream>>>(part, head_w, head_b, out);
  }
}

// Round 13
// 204.735 us; speedup vs baseline: 7.7963x; 7.7963x over previous
//
#include <hip/hip_runtime.h>
#include <hip/hip_bf16.h>
#include <math.h>

#define DV 256
#define NSEQ 1024
#define HHEADS 8
#define VV 32000
#define QKSCALE 0.17677669529663687f  // 1/sqrt(32)

typedef __attribute__((ext_vector_type(8))) short short8v;
typedef __attribute__((ext_vector_type(4))) float f32x4;

__device__ __forceinline__ unsigned short f2bf(float f){
  __hip_bfloat16 b = __float2bfloat16(f);
  return *reinterpret_cast<unsigned short*>(&b);
}
__device__ __forceinline__ float bfbits2f(unsigned short u){
  unsigned int x = ((unsigned int)u) << 16;
  return __uint_as_float(x);
}
// XCD-aware swizzle: blocks b -> XCD b%8 (HW round-robin); remap so wid-contiguous
// work (which shares operand panels) is XCD-contiguous. Requires nwg%8==0.
__device__ __forceinline__ int xcd_swz(int lin, int nwg){
  return (lin & 7) * (nwg >> 3) + (lin >> 3);
}

#define OFF_WQKVP 0
#define OFF_WOT   425984
#define OFF_F1T   557056
#define OFF_F2T   1081344
__global__ __launch_bounds__(256) void transpose_cvt_all(
    const float* __restrict__ Wq, const float* __restrict__ Wk,
    const float* __restrict__ Wv, const float* __restrict__ Wo,
    const float* __restrict__ ppw, const float* __restrict__ f1w,
    const float* __restrict__ f2w, __hip_bfloat16* __restrict__ dst){
  __shared__ float sh[32][33];
  int bid = blockIdx.x;
  int t = threadIdx.x;
  if(bid >= 512 && bid < 528){
    int idx = bid - 512;
    int l = idx >> 3, k0 = (idx & 7) * 32;
    int rowo = t >> 2;
    int kbase = k0 + (t & 3) * 8;
    unsigned short vals[8];
    if(rowo < 8){
      int hh = rowo;
      #pragma unroll
      for(int i=0;i<8;i++) vals[i] = f2bf(ppw[(long)l*2048 + (kbase+i)*HHEADS + hh]);
    } else {
      #pragma unroll
      for(int i=0;i<8;i++) vals[i] = 0;
    }
    unsigned short* d = (unsigned short*)dst + (long)l*212992 + (768+rowo)*256 + kbase;
    #pragma unroll
    for(int i=0;i<8;i++) d[i] = vals[i];
    return;
  }
  const float* src; __hip_bfloat16* d; int K, N, tile;
  if(bid < 384){
    int l = bid / 192, rem = bid % 192, mat = rem >> 6; tile = rem & 63;
    src = (mat==0 ? Wq : (mat==1 ? Wk : Wv)) + l*65536;
    d = dst + (long)l*212992 + mat*65536;
    K = 256; N = 256;
  } else if(bid < 512){
    int b2 = bid - 384; int l = b2 >> 6; tile = b2 & 63;
    src = Wo + l*65536; d = dst + OFF_WOT + l*65536; K = 256; N = 256;
  } else if(bid < 1040){
    int b2 = bid - 528; int l = b2 >> 8; tile = b2 & 255;
    src = f1w + l*262144; d = dst + OFF_F1T + l*262144; K = 256; N = 1024;
  } else {
    int b2 = bid - 1040; int l = b2 >> 8; tile = b2 & 255;
    src = f2w + l*262144; d = dst + OFF_F2T + l*262144; K = 1024; N = 256;
  }
  int ntn = N >> 5;
  int tk = tile / ntn, tn = tile - tk*ntn;
  int k0 = tk*32, n0 = tn*32;
  {
    int rr = t >> 3, cc = (t & 7) * 4;
    float4 v = *(const float4*)&src[(long)(k0+rr)*N + n0 + cc];
    sh[rr][cc]=v.x; sh[rr][cc+1]=v.y; sh[rr][cc+2]=v.z; sh[rr][cc+3]=v.w;
  }
  __syncthreads();
  int nn = t >> 3, kk = (t & 7) * 4;
  ushort4 o;
  o.x = f2bf(sh[kk+0][nn]);
  o.y = f2bf(sh[kk+1][nn]);
  o.z = f2bf(sh[kk+2][nn]);
  o.w = f2bf(sh[kk+3][nn]);
  *(ushort4*)&((unsigned short*)d)[(long)(n0+nn)*K + k0 + kk] = o;
}

// ---------------- embedding + LN (writes f32 h + bf16 hb) ----------------
__global__ __launch_bounds__(256) void embed_ln_kernel(
    const int* __restrict__ ids, const float* __restrict__ tok, const float* __restrict__ pos,
    const float* __restrict__ g, const float* __restrict__ bt,
    float* __restrict__ h, __hip_bfloat16* __restrict__ hb){
  int t = threadIdx.x;
  int lane = t & 63;
  int row = blockIdx.x*4 + (t >> 6);
  int n = row & (NSEQ-1);
  int id = ids[row];
  float4 vv = ((const float4*)tok)[(long)id*64 + lane];
  float4 pv = ((const float4*)pos)[n*64 + lane];
  vv.x += pv.x; vv.y += pv.y; vv.z += pv.z; vv.w += pv.w;
  float s  = vv.x+vv.y+vv.z+vv.w;
  float s2 = vv.x*vv.x+vv.y*vv.y+vv.z*vv.z+vv.w*vv.w;
  #pragma unroll
  for(int off=1; off<64; off<<=1){ s += __shfl_xor(s, off); s2 += __shfl_xor(s2, off); }
  float mean = s*(1.f/DV);
  float var = fmaxf(s2*(1.f/DV) - mean*mean, 0.f);
  float inv = rsqrtf(var + 1e-5f);
  float4 gv = ((const float4*)g)[lane];
  float4 bv = ((const float4*)bt)[lane];
  float4 o;
  o.x=(vv.x-mean)*inv*gv.x+bv.x; o.y=(vv.y-mean)*inv*gv.y+bv.y;
  o.z=(vv.z-mean)*inv*gv.z+bv.z; o.w=(vv.w-mean)*inv*gv.w+bv.w;
  ((float4*)h)[row*64 + lane] = o;
  ushort4 ob; ob.x=f2bf(o.x); ob.y=f2bf(o.y); ob.z=f2bf(o.z); ob.w=f2bf(o.w);
  *(ushort4*)&hb[row*DV + lane*4] = ob;
}

// ---------------- (residual +) LN standalone (wave-per-row) ----------------
__global__ __launch_bounds__(256) void ln_res_kernel(
    const float* __restrict__ x, const float* __restrict__ r,
    float* __restrict__ out, __hip_bfloat16* __restrict__ outb,
    const float* __restrict__ g, const float* __restrict__ bt){
  int t = threadIdx.x;
  int lane = t & 63;
  int row = blockIdx.x*4 + (t >> 6);
  float4 vv = ((const float4*)x)[row*64 + lane];
  float4 rv = ((const float4*)r)[row*64 + lane];
  vv.x += rv.x; vv.y += rv.y; vv.z += rv.z; vv.w += rv.w;
  float s  = vv.x+vv.y+vv.z+vv.w;
  float s2 = vv.x*vv.x+vv.y*vv.y+vv.z*vv.z+vv.w*vv.w;
  #pragma unroll
  for(int off=1; off<64; off<<=1){ s += __shfl_xor(s, off); s2 += __shfl_xor(s2, off); }
  float mean = s*(1.f/DV);
  float var = fmaxf(s2*(1.f/DV) - mean*mean, 0.f);
  float inv = rsqrtf(var + 1e-5f);
  float4 gv = ((const float4*)g)[lane];
  float4 bv = ((const float4*)bt)[lane];
  float4 o;
  o.x=(vv.x-mean)*inv*gv.x+bv.x; o.y=(vv.y-mean)*inv*gv.y+bv.y;
  o.z=(vv.z-mean)*inv*gv.z+bv.z; o.w=(vv.w-mean)*inv*gv.w+bv.w;
  ((float4*)out)[row*64 + lane] = o;
  ushort4 ob; ob.x=f2bf(o.x); ob.y=f2bf(o.y); ob.z=f2bf(o.z); ob.w=f2bf(o.w);
  *(ushort4*)&outb[row*DV + lane*4] = ob;
}

// ---------------- generic pipelined bf16 MFMA GEMM (BK=128) + XCD swizzle ----------------
template<int WM, int WN, int FM, int FN, int ACT, int OUT_BF16, int PHASE>
__global__ __launch_bounds__(256) void mfma_gemm(
    const __hip_bfloat16* __restrict__ A, const __hip_bfloat16* __restrict__ Bt,
    const float* __restrict__ bias, void* __restrict__ Cout,
    int M, int N, int K, int ldc,
    const float* __restrict__ pb, float* __restrict__ cph, float* __restrict__ sph){
  constexpr int BM = WM*FM*16;
  constexpr int BN = WN*FN*16;
  constexpr int TPRA = 256/BM;
  constexpr int JA = 16/TPRA;
  __shared__ short As[2][BM][136];
  __shared__ short Bs[2][BN][136];
  int nwg = gridDim.x * gridDim.y;
  int lin = blockIdx.x + blockIdx.y * gridDim.x;
  int wid = (nwg & 7) ? lin : xcd_swz(lin, nwg);
  int bx = wid % gridDim.x, by = wid / gridDim.x;
  int tm = bx*BM, tn = by*BN;
  int t = threadIdx.x;
  int lane = t & 63, w = t >> 6;
  int wm = w / WN, wn = w % WN;
  int lr = lane & 15, lg = lane >> 4;
  f32x4 acc[FM][FN] = {};
  const short* gA = (const short*)A;
  const short* gB = (const short*)Bt;
  int ra = t / TPRA, ca = t % TPRA;
  int rb = t >> 2,  cb = t & 3;
  short8v ar[JA], br[4];
#define LOADC(K0) { const short* pa = &gA[(long)(tm+ra)*K + (K0)]; \
    _Pragma("unroll") for(int j=0;j<JA;j++) ar[j] = *(const short8v*)&pa[(ca+TPRA*j)*8]; \
    const short* pbp = &gB[(long)(tn+rb)*K + (K0)]; \
    _Pragma("unroll") for(int j=0;j<4;j++) br[j] = *(const short8v*)&pbp[(cb+4*j)*8]; }
#define STOREC(BUF) { _Pragma("unroll") for(int j=0;j<JA;j++) *(short8v*)&As[BUF][ra][(ca+TPRA*j)*8] = ar[j]; \
    _Pragma("unroll") for(int j=0;j<4;j++) *(short8v*)&Bs[BUF][rb][(cb+4*j)*8] = br[j]; }
  int nch = K >> 7;
  LOADC(0);
  STOREC(0);
  if(nch > 1) LOADC(128);
  __syncthreads();
  for(int c=0; c<nch; c++){
    int cur = c & 1;
    #pragma unroll
    for(int ks=0; ks<4; ks++){
      short8v af[FM], bf[FN];
      #pragma unroll
      for(int i=0;i<FM;i++) af[i] = *(const short8v*)&As[cur][wm*FM*16 + i*16 + lr][ks*32 + lg*8];
      #pragma unroll
      for(int j=0;j<FN;j++) bf[j] = *(const short8v*)&Bs[cur][wn*FN*16 + j*16 + lr][ks*32 + lg*8];
      #pragma unroll
      for(int i=0;i<FM;i++)
        #pragma unroll
        for(int j=0;j<FN;j++)
          acc[i][j] = __builtin_amdgcn_mfma_f32_16x16x32_bf16(af[i], bf[j], acc[i][j], 0,0,0);
    }
    if(c+1 < nch){
      STOREC(cur^1);
      if(c+2 < nch) LOADC((c+2)*128);
    }
    __syncthreads();
  }
#undef LOADC
#undef STOREC
  if(PHASE && tn >= N - 64){
    #pragma unroll
    for(int fn=0; fn<FN; fn++){
      int colr = wn*FN*16 + fn*16 + lr;
      if(colr < 8){
        float bb = pb[colr];
        #pragma unroll
        for(int fm=0; fm<FM; fm++){
          int row0 = tm + wm*FM*16 + fm*16 + lg*4;
          #pragma unroll
          for(int r2=0; r2<4; r2++){
            float ph = acc[fm][fn][r2] + bb;
            float sv, cv;
            __sincosf(ph, &sv, &cv);
            int row = row0 + r2;
            int b = row >> 10, n = row & 1023;
            int idx = (b*HHEADS + colr)*NSEQ + n;
            cph[idx] = cv; sph[idx] = sv;
          }
        }
      }
    }
    return;
  }
  #pragma unroll
  for(int fn=0; fn<FN; fn++){
    int col = tn + wn*FN*16 + fn*16 + lr;
    float bs = bias ? bias[col] : 0.f;
    #pragma unroll
    for(int fm=0; fm<FM; fm++){
      int row0 = tm + wm*FM*16 + fm*16 + lg*4;
      #pragma unroll
      for(int r2=0; r2<4; r2++){
        float xx = acc[fm][fn][r2] + bs;
        if(ACT == 1) xx = 0.5f*xx*(1.f + erff(xx*0.70710678118654752f));
        long idx = (long)(row0+r2)*ldc + col;
        if(OUT_BF16) ((__hip_bfloat16*)Cout)[idx] = __float2bfloat16(xx);
        else         ((float*)Cout)[idx] = xx;
      }
    }
  }
}

// ---------------- MFMA flash attention: split-K x4, static softmax, double-buffered ----------------
__global__ __launch_bounds__(256) void attn_mfma_kernel(
    const __hip_bfloat16* __restrict__ qkv,
    const float* __restrict__ cph, const float* __restrict__ sph,
    __hip_bfloat16* __restrict__ po, float* __restrict__ ml){
  __shared__ __align__(16) short K2[2][64][104];
  __shared__ __align__(16) short V2[2][32][72];
  __shared__ __align__(16) short Pp[4][16][72];
  int bid = xcd_swz(blockIdx.x, gridDim.x);
  int bh = bid >> 6;
  int qt = (bid >> 2) & 15;
  int ks = bid & 3;
  int b = bh >> 3, hh = bh & 7;
  int t = threadIdx.x;
  int lane = t & 63, w = t >> 6;
  int lr = lane & 15, lg = lane >> 4;
  int q0w = qt*64 + w*16;

  const unsigned short* qrow = (const unsigned short*)qkv
      + ((long)(b*NSEQ + q0w + lr))*768 + hh*32 + lg*8;
  short8v qraw = *(const short8v*)qrow;
  float ci = cph[bh*NSEQ + q0w + lr];
  float si = sph[bh*NSEQ + q0w + lr];
  short8v qf0, qf1, qf2;
  #pragma unroll
  for(int i=0;i<8;i++){
    float x = bfbits2f((unsigned short)qraw[i]) * (0.5f*QKSCALE);
    qf0[i] = (short)f2bf(x);
    qf1[i] = (short)f2bf(x*ci);
    qf2[i] = (short)f2bf(x*si);
  }

  int srow = t >> 2, sdc = (t & 3) * 8;
  int j0b = ks*4;
  short8v kv, vvr; float cj, sj;
#define LOADT(J) { long rg = (long)(b*NSEQ + (J)*64 + srow)*768; \
    kv  = *(const short8v*)((const unsigned short*)qkv + rg + 256 + hh*32 + sdc); \
    vvr = *(const short8v*)((const unsigned short*)qkv + rg + 512 + hh*32 + sdc); \
    cj = cph[bh*NSEQ + (J)*64 + srow]; sj = sph[bh*NSEQ + (J)*64 + srow]; }
#define STORET(BUF) { short8v kc, ksv; \
    _Pragma("unroll") for(int i=0;i<8;i++){ float x = bfbits2f((unsigned short)kv[i]); \
      kc[i] = (short)f2bf(x*cj); ksv[i] = (short)f2bf(x*sj); } \
    *(short8v*)&K2[BUF][srow][sdc]    = kv; \
    *(short8v*)&K2[BUF][srow][32+sdc] = kc; \
    *(short8v*)&K2[BUF][srow][64+sdc] = ksv; \
    _Pragma("unroll") for(int i=0;i<8;i++) V2[BUF][sdc+i][srow] = vvr[i]; }

  float l = 0.f;
  f32x4 acc[2] = {};

  LOADT(j0b);
  STORET(0);
  LOADT(j0b+1);
  __syncthreads();
  for(int j=0; j<4; j++){
    int cur = j & 1;
    f32x4 st[4];
    #pragma unroll
    for(int kt=0; kt<4; kt++){
      short8v a0 = *(const short8v*)&K2[cur][kt*16+lr][lg*8];
      short8v a1 = *(const short8v*)&K2[cur][kt*16+lr][32+lg*8];
      short8v a2 = *(const short8v*)&K2[cur][kt*16+lr][64+lg*8];
      f32x4 z = {0.f,0.f,0.f,0.f};
      z = __builtin_amdgcn_mfma_f32_16x16x32_bf16(a0, qf0, z, 0,0,0);
      z = __builtin_amdgcn_mfma_f32_16x16x32_bf16(a1, qf1, z, 0,0,0);
      z = __builtin_amdgcn_mfma_f32_16x16x32_bf16(a2, qf2, z, 0,0,0);
      st[kt] = z;
    }
    float ls = 0.f;
    #pragma unroll
    for(int kt=0; kt<4; kt++){
      float p0 = __expf(st[kt][0]);
      float p1 = __expf(st[kt][1]);
      float p2 = __expf(st[kt][2]);
      float p3 = __expf(st[kt][3]);
      ls += (p0+p1)+(p2+p3);
      unsigned int w0 = (unsigned)f2bf(p0) | ((unsigned)f2bf(p1)<<16);
      unsigned int w1 = (unsigned)f2bf(p2) | ((unsigned)f2bf(p3)<<16);
      unsigned int* pp = (unsigned int*)&Pp[w][lr][kt*16 + lg*4];
      pp[0] = w0; pp[1] = w1;
    }
    ls += __shfl_xor(ls, 16);
    ls += __shfl_xor(ls, 32);
    l += ls;
    #pragma unroll
    for(int kk=0; kk<2; kk++){
      short8v pa  = *(const short8v*)&Pp[w][lr][kk*32 + lg*8];
      short8v vf0 = *(const short8v*)&V2[cur][lr][kk*32 + lg*8];
      short8v vf1 = *(const short8v*)&V2[cur][16+lr][kk*32 + lg*8];
      acc[0] = __builtin_amdgcn_mfma_f32_16x16x32_bf16(pa, vf0, acc[0], 0,0,0);
      acc[1] = __builtin_amdgcn_mfma_f32_16x16x32_bf16(pa, vf1, acc[1], 0,0,0);
    }
    if(j < 3){
      STORET(cur^1);
      if(j < 2) LOADT(j0b+j+2);
    }
    __syncthreads();
  }
#undef LOADT
#undef STORET
  if(lane < 16){
    ml[((long)(ks*16+bh))*NSEQ + q0w + lr] = l;
  }
  #pragma unroll
  for(int dt=0; dt<2; dt++)
    #pragma unroll
    for(int r=0;r<4;r++){
      int row = q0w + lg*4 + r;
      po[(((long)(ks*16+bh))*NSEQ + row)*32 + dt*16 + lr] =
          __float2bfloat16(acc[dt][r]);
    }
}

// ---------------- wo_ln: combine(x4) + @Wo + residual + LN1, 16-row stripes ----------------
__global__ __launch_bounds__(256) void wo_ln_kernel(
    const __hip_bfloat16* __restrict__ po, const float* __restrict__ ml,
    const __hip_bfloat16* __restrict__ Bt, const float* __restrict__ hres,
    const float* __restrict__ lng, const float* __restrict__ lnb,
    float* __restrict__ h1, __hip_bfloat16* __restrict__ hb1){
  __shared__ short As[16][264];
  __shared__ short Bs[64][264];
  __shared__ float Co[16][260];
  int tm = blockIdx.x*16;
  int t = threadIdx.x;
  int lane = t & 63, w = t >> 6;
  int lr = lane & 15, lg = lane >> 4;
  {
    int r = t >> 4;
    int c16 = (t & 15) * 16;
    int R = tm + r; int b = R >> 10, q = R & 1023;
    int bh = b*HHEADS + (c16 >> 5);
    long mlb = (long)bh*NSEQ + q;
    float lsum = ml[mlb] + ml[mlb + 16*NSEQ] + ml[mlb + 32*NSEQ] + ml[mlb + 48*NSEQ];
    float inv = 1.f/lsum;
    long pob = ((long)bh*NSEQ + q)*32 + (c16 & 31);
    const unsigned short* pp = (const unsigned short*)po;
    #pragma unroll
    for(int i=0;i<2;i++){
      short8v a0 = *(const short8v*)&pp[pob + i*8];
      short8v a1 = *(const short8v*)&pp[pob + (long)16*NSEQ*32 + i*8];
      short8v a2 = *(const short8v*)&pp[pob + (long)32*NSEQ*32 + i*8];
      short8v a3 = *(const short8v*)&pp[pob + (long)48*NSEQ*32 + i*8];
      short8v o;
      #pragma unroll
      for(int k=0;k<8;k++)
        o[k] = (short)f2bf((bfbits2f((unsigned short)a0[k]) + bfbits2f((unsigned short)a1[k])
                          + bfbits2f((unsigned short)a2[k]) + bfbits2f((unsigned short)a3[k]))*inv);
      *(short8v*)&As[r][c16 + i*8] = o;
    }
  }
  const short* gB = (const short*)Bt;
  int rb = t >> 2, cb = t & 3;
  {
    const short* pbp = &gB[(long)rb*256];
    #pragma unroll
    for(int j=0;j<8;j++) *(short8v*)&Bs[rb][(cb+4*j)*8] = *(const short8v*)&pbp[(cb+4*j)*8];
  }
  __syncthreads();
  f32x4 acc[4] = {};
  for(int ct=0; ct<4; ct++){
    #pragma unroll
    for(int ksx=0; ksx<8; ksx++){
      short8v af = *(const short8v*)&As[lr][ksx*32 + lg*8];
      short8v bf = *(const short8v*)&Bs[w*16+lr][ksx*32 + lg*8];
      acc[ct] = __builtin_amdgcn_mfma_f32_16x16x32_bf16(af, bf, acc[ct], 0,0,0);
    }
    if(ct < 3){
      __syncthreads();
      const short* pbp = &gB[(long)((ct+1)*64 + rb)*256];
      #pragma unroll
      for(int j=0;j<8;j++) *(short8v*)&Bs[rb][(cb+4*j)*8] = *(const short8v*)&pbp[(cb+4*j)*8];
      __syncthreads();
    }
  }
  #pragma unroll
  for(int ct=0; ct<4; ct++)
    #pragma unroll
    for(int r2=0; r2<4; r2++)
      Co[lg*4 + r2][ct*64 + w*16 + lr] = acc[ct][r2];
  __syncthreads();
  {
    int r = t >> 4;
    int c16 = (t & 15) * 16;
    int R = tm + r;
    float v[16];
    float s = 0.f, s2 = 0.f;
    const float* hr = hres + (long)R*DV + c16;
    #pragma unroll
    for(int i=0;i<4;i++){
      float4 hv = *(const float4*)&hr[4*i];
      float x0 = Co[r][c16+4*i]   + hv.x;
      float x1 = Co[r][c16+4*i+1] + hv.y;
      float x2 = Co[r][c16+4*i+2] + hv.z;
      float x3 = Co[r][c16+4*i+3] + hv.w;
      v[4*i]=x0; v[4*i+1]=x1; v[4*i+2]=x2; v[4*i+3]=x3;
      s += x0+x1+x2+x3;
      s2 += x0*x0+x1*x1+x2*x2+x3*x3;
    }
    s += __shfl_xor(s,1); s2 += __shfl_xor(s2,1);
    s += __shfl_xor(s,2); s2 += __shfl_xor(s2,2);
    s += __shfl_xor(s,4); s2 += __shfl_xor(s2,4);
    s += __shfl_xor(s,8); s2 += __shfl_xor(s2,8);
    float mean = s*(1.f/DV);
    float var = fmaxf(s2*(1.f/DV) - mean*mean, 0.f);
    float invs = rsqrtf(var + 1e-5f);
    #pragma unroll
    for(int i=0;i<4;i++){
      int col = c16 + 4*i;
      float4 gv = *(const float4*)&lng[col];
      float4 bv = *(const float4*)&lnb[col];
      float o0 = (v[4*i+0]-mean)*invs*gv.x + bv.x;
      float o1 = (v[4*i+1]-mean)*invs*gv.y + bv.y;
      float o2 = (v[4*i+2]-mean)*invs*gv.z + bv.z;
      float o3 = (v[4*i+3]-mean)*invs*gv.w + bv.w;
      *(float4*)&h1[(long)R*DV + col] = make_float4(o0,o1,o2,o3);
      ushort4 ob; ob.x=f2bf(o0); ob.y=f2bf(o1); ob.z=f2bf(o2); ob.w=f2bf(o3);
      *(ushort4*)&hb1[(long)R*DV + col] = ob;
    }
  }
}

// ---------------- final: LN2 -> outLN -> column partial sums ----------------
__global__ __launch_bounds__(256) void final_pool_kernel(
    const float* __restrict__ x, const float* __restrict__ r,
    const float* __restrict__ g2, const float* __restrict__ b2,
    const float* __restrict__ og, const float* __restrict__ ob,
    float* __restrict__ part){
  __shared__ float ws2[32][260];
  int t = threadIdx.x;
  int lrow = t >> 3;
  int row = blockIdx.x*32 + lrow;
  int c0 = (t & 7) * 32;
  float v[32];
  float s=0.f, s2=0.f;
  const float* xr = x + (long)row*DV + c0;
  const float* rr = r + (long)row*DV + c0;
  #pragma unroll
  for(int i=0;i<8;i++){
    float4 xv = *(const float4*)&xr[4*i];
    float4 rv = *(const float4*)&rr[4*i];
    xv.x+=rv.x; xv.y+=rv.y; xv.z+=rv.z; xv.w+=rv.w;
    v[4*i]=xv.x; v[4*i+1]=xv.y; v[4*i+2]=xv.z; v[4*i+3]=xv.w;
    s += xv.x+xv.y+xv.z+xv.w;
    s2 += xv.x*xv.x+xv.y*xv.y+xv.z*xv.z+xv.w*xv.w;
  }
  s += __shfl_xor(s,1); s2 += __shfl_xor(s2,1);
  s += __shfl_xor(s,2); s2 += __shfl_xor(s2,2);
  s += __shfl_xor(s,4); s2 += __shfl_xor(s2,4);
  float mean = s*(1.f/DV);
  float var = fmaxf(s2*(1.f/DV)-mean*mean, 0.f);
  float inv = rsqrtf(var + 1e-5f);
  float s_=0.f, s2_=0.f;
  #pragma unroll
  for(int i=0;i<32;i++){
    int col = c0 + i;
    float o = (v[i]-mean)*inv*g2[col] + b2[col];
    v[i] = o;
    s_ += o; s2_ += o*o;
  }
  s_ += __shfl_xor(s_,1); s2_ += __shfl_xor(s2_,1);
  s_ += __shfl_xor(s_,2); s2_ += __shfl_xor(s2_,2);
  s_ += __shfl_xor(s_,4); s2_ += __shfl_xor(s2_,4);
  float mean2 = s_*(1.f/DV);
  float var2 = fmaxf(s2_*(1.f/DV)-mean2*mean2, 0.f);
  float inv2 = rsqrtf(var2 + 1e-5f);
  #pragma unroll
  for(int i=0;i<32;i++){
    int col = c0 + i;
    ws2[lrow][col] = (v[i]-mean2)*inv2*og[col] + ob[col];
  }
  __syncthreads();
  float accv = 0.f;
  #pragma unroll 8
  for(int rr2=0; rr2<32; rr2++) accv += ws2[rr2][t];
  part[blockIdx.x*DV + t] = accv;
}

// ---------------- head: reduce partials + matvec (250 blocks x 128 thr) ----------------
__global__ __launch_bounds__(128) void head_kernel(
    const float* __restrict__ part, const float* __restrict__ W,
    const float* __restrict__ hb, float* __restrict__ out){
  __shared__ float pooled[2][256];
  int t = threadIdx.x;
  for(int cc=t; cc<256; cc+=128){
    float a0 = 0.f, a1 = 0.f;
    #pragma unroll 8
    for(int k=0;k<32;k++){ a0 += part[k*DV + cc]; a1 += part[(32+k)*DV + cc]; }
    pooled[0][cc] = a0 * (1.f/NSEQ);
    pooled[1][cc] = a1 * (1.f/NSEQ);
  }
  __syncthreads();
  int vcol = blockIdx.x*128 + t;
  float x0 = 0.f, x1 = 0.f;
  #pragma unroll 8
  for(int d=0; d<DV; d++){
    float wv = W[(long)d*VV + vcol];
    x0 += pooled[0][d]*wv;
    x1 += pooled[1][d]*wv;
  }
  float bb = hb[vcol];
  out[vcol] = x0 + bb;
  out[VV + vcol] = x1 + bb;
}

extern "C" void kernel_launch(void* const* d_in, const int* in_sizes, int n_in,
                              void* d_out, int out_size, void* d_ws, size_t ws_size,
                              hipStream_t stream){
  const int*   ids   = (const int*)  d_in[0];
  const float* tok   = (const float*)d_in[1];
  const float* pos   = (const float*)d_in[2];
  const float* en_g  = (const float*)d_in[3];
  const float* en_b  = (const float*)d_in[4];
  const float* Wq    = (const float*)d_in[7];
  const float* Wk    = (const float*)d_in[8];
  const float* Wv    = (const float*)d_in[9];
  const float* Wo    = (const float*)d_in[10];
  const float* pp_w  = (const float*)d_in[11];
  const float* pp_b  = (const float*)d_in[12];
  const float* f1_w  = (const float*)d_in[13];
  const float* f1_b  = (const float*)d_in[14];
  const float* f2_w  = (const float*)d_in[15];
  const float* f2_b  = (const float*)d_in[16];
  const float* ln1_g = (const float*)d_in[17];
  const float* ln1_b = (const float*)d_in[18];
  const float* ln2_g = (const float*)d_in[19];
  const float* ln2_b = (const float*)d_in[20];
  const float* on_g  = (const float*)d_in[23];
  const float* on_b  = (const float*)d_in[24];
  const float* head_w= (const float*)d_in[25];
  const float* head_b= (const float*)d_in[26];
  float* out = (float*)d_out;

  char* wsb = (char*)d_ws;
  float* h    = (float*)(wsb);
  __hip_bfloat16* hb  = (__hip_bfloat16*)(wsb + (2u<<20));
  float* h1   = (float*)(wsb + (3u<<20));
  __hip_bfloat16* hb1 = (__hip_bfloat16*)(wsb + (5u<<20));
  __hip_bfloat16* qkv = (__hip_bfloat16*)(wsb + (6u<<20));
  __hip_bfloat16* po  = (__hip_bfloat16*)(wsb + (9u<<20));
  float* mlb  = (float*)(wsb + (13u<<20));
  __hip_bfloat16* ff  = (__hip_bfloat16*)(wsb + (14u<<20));
  float* s_ff = (float*)(wsb + (18u<<20));
  float* cphb = (float*)(wsb + (20u<<20));
  float* sphb = cphb + 16384;
  float* part = sphb + 16384;
  __hip_bfloat16* wt = (__hip_bfloat16*)(wsb + (20u<<20) + (192u<<10));
  __hip_bfloat16* wqkvp = wt + OFF_WQKVP;
  __hip_bfloat16* wot   = wt + OFF_WOT;
  __hip_bfloat16* f1t   = wt + OFF_F1T;
  __hip_bfloat16* f2t   = wt + OFF_F2T;

  transpose_cvt_all<<<1552, 256, 0, stream>>>(Wq, Wk, Wv, Wo, pp_w, f1_w, f2_w, wt);
  embed_ln_kernel<<<512, 256, 0, stream>>>(ids, tok, pos, en_g, en_b, h, hb);

  for(int it=0; it<4; it++){
    int l = it & 1;
    mfma_gemm<2,2,2,2, 0,1,1><<<dim3(32,13), 256, 0, stream>>>(
        hb, wqkvp + (long)l*212992, nullptr, qkv, 2048, 832, 256, 768,
        pp_b + l*HHEADS, cphb, sphb);
    attn_mfma_kernel<<<1024, 256, 0, stream>>>(qkv, cphb, sphb, po, mlb);
    wo_ln_kernel<<<128, 256, 0, stream>>>(
        po, mlb, wot + l*65536, h, ln1_g + l*DV, ln1_b + l*DV, h1, hb1);
    mfma_gemm<2,2,2,2, 1,1,0><<<dim3(32,16), 256, 0, stream>>>(
        hb1, f1t + l*262144, f1_b + l*1024, ff, 2048, 1024, 256, 1024,
        nullptr, nullptr, nullptr);
    mfma_gemm<1,4,2,1, 0,0,0><<<dim3(64,4), 256, 0, stream>>>(
        ff, f2t + l*262144, f2_b + l*DV, s_ff, 2048, 256, 1024, 256,
        nullptr, nullptr, nullptr);
    if(it < 3)
      ln_res_kernel<<<512, 256, 0, stream>>>(s_ff, h1, h, hb, ln2_g + l*DV, ln2_b + l*DV);
  }
  final_pool_kernel<<<64, 256, 0, stream>>>(s_ff, h1, ln2_g + DV, ln2_b + DV, on_g, on_b, part);
  head_kernel<<<250, 128, 0, stream>>>(part, head_w, head_b, out);
}